// Round 2
// baseline (643.297 us; speedup 1.0000x reference)
//
#include <hip/hip_runtime.h>
#include <hip/hip_bf16.h>

// Problem constants
#define BATCH 2
#define LSEQ 2048
#define DMODEL 1024
#define NH 16
#define DQK 16
#define DV 64
#define FDIM 273            // 1 + 16 + 256
#define CHUNK 128
#define NCH (LSEQ / CHUNK)  // 16 chunks per batch row
#define ROWS (BATCH * LSEQ) // 4096
#define C2 0.17677669529663687f  // 1/(4*sqrt(2))

// ---------------------------------------------------------------------------
// Tiled fp32 GEMM: C(MxN) = A(MxK) @ B(KxN), all row-major fp32.
// 64x64 tile, 256 threads, BK=16, 4x4 micro-tile per thread.
// ---------------------------------------------------------------------------
__global__ __launch_bounds__(256) void gemm_f32(
    const float* __restrict__ A, const float* __restrict__ Bw,
    float* __restrict__ Cc, int M, int N, int K) {
  __shared__ float As[16][68];  // [k][m], +4 pad keeps float4 rows 16B-aligned
  __shared__ float Bs[16][68];  // [k][n]
  const int tid = threadIdx.x;
  const int bm = blockIdx.y * 64;
  const int bn = blockIdx.x * 64;
  const int tx = tid & 15, ty = tid >> 4;
  const int la_r = tid >> 2, la_k = (tid & 3) * 4;   // A: 64 rows x 16 k
  const int lb_r = tid >> 4, lb_c = (tid & 15) * 4;  // B: 16 k x 64 n
  float acc[4][4] = {};
  for (int k0 = 0; k0 < K; k0 += 16) {
    float4 fa = *(const float4*)(A + (size_t)(bm + la_r) * K + k0 + la_k);
    float4 fb = *(const float4*)(Bw + (size_t)(k0 + lb_r) * N + bn + lb_c);
    As[la_k + 0][la_r] = fa.x; As[la_k + 1][la_r] = fa.y;
    As[la_k + 2][la_r] = fa.z; As[la_k + 3][la_r] = fa.w;
    Bs[lb_r][lb_c + 0] = fb.x; Bs[lb_r][lb_c + 1] = fb.y;
    Bs[lb_r][lb_c + 2] = fb.z; Bs[lb_r][lb_c + 3] = fb.w;
    __syncthreads();
#pragma unroll
    for (int kk = 0; kk < 16; kk++) {
      float4 av = *(const float4*)&As[kk][ty * 4];
      float4 bv = *(const float4*)&Bs[kk][tx * 4];
      float am[4] = {av.x, av.y, av.z, av.w};
      float bb[4] = {bv.x, bv.y, bv.z, bv.w};
#pragma unroll
      for (int i2 = 0; i2 < 4; i2++)
#pragma unroll
        for (int j2 = 0; j2 < 4; j2++) acc[i2][j2] += am[i2] * bb[j2];
    }
    __syncthreads();
  }
#pragma unroll
  for (int i2 = 0; i2 < 4; i2++) {
    float4 st = make_float4(acc[i2][0], acc[i2][1], acc[i2][2], acc[i2][3]);
    *(float4*)(Cc + (size_t)(bm + ty * 4 + i2) * N + bn + tx * 4) = st;
  }
}

// ---------------------------------------------------------------------------
// Pass 1: per-(b,h,chunk) sums  S_c[f][e] = sum_i kf_i[f] * v_i[e],
//         u_c[f] = sum_i kf_i[f].  kf computed on the fly from 16-dim k.
// ---------------------------------------------------------------------------
__global__ __launch_bounds__(256) void chunk_sums(
    const float* __restrict__ kbuf, const float* __restrict__ vbuf,
    float* __restrict__ Sbuf, float* __restrict__ ubuf) {
  const int c = blockIdx.x, bh = blockIdx.y;
  const int b = bh >> 4, h = bh & 15;
  __shared__ float ks[CHUNK][DQK];
  __shared__ float vs[CHUNK][DV];
  const int tid = threadIdx.x;
  const int row0 = b * LSEQ + c * CHUNK;
  for (int idx = tid; idx < CHUNK * DQK; idx += 256) {
    int i = idx >> 4, d = idx & 15;
    ks[i][d] = kbuf[(size_t)(row0 + i) * (NH * DQK) + h * DQK + d];
  }
  for (int idx = tid; idx < CHUNK * DV; idx += 256) {
    int i = idx >> 6, d = idx & 63;
    vs[i][d] = vbuf[(size_t)(row0 + i) * (NH * DV) + h * DV + d];
  }
  __syncthreads();
  for (int f = tid; f < FDIM; f += 256) {
    float4 acc[16];
#pragma unroll
    for (int r = 0; r < 16; r++) acc[r] = make_float4(0.f, 0.f, 0.f, 0.f);
    float usum = 0.f;
    const int a1 = (f == 0) ? 0 : ((f < 17) ? (f - 1) : ((f - 17) >> 4));
    const int b1 = (f >= 17) ? ((f - 17) & 15) : 0;
    for (int i = 0; i < CHUNK; i++) {
      float kf;
      if (f == 0) kf = 1.0f;
      else if (f < 17) kf = 0.5f * ks[i][a1];
      else kf = C2 * ks[i][a1] * ks[i][b1];
      usum += kf;
      const float4* vr = (const float4*)&vs[i][0];
#pragma unroll
      for (int r = 0; r < 16; r++) {
        float4 vv = vr[r];
        acc[r].x += kf * vv.x; acc[r].y += kf * vv.y;
        acc[r].z += kf * vv.z; acc[r].w += kf * vv.w;
      }
    }
    float* Sout = Sbuf + (((size_t)bh * NCH + c) * FDIM + f) * DV;
#pragma unroll
    for (int r = 0; r < 16; r++) ((float4*)Sout)[r] = acc[r];
    ubuf[((size_t)bh * NCH + c) * FDIM + f] = usum;
  }
}

// ---------------------------------------------------------------------------
// Pass 2: in-place exclusive prefix over chunks for S and u.
// ---------------------------------------------------------------------------
__global__ __launch_bounds__(64) void prefix_scan(float* __restrict__ Sbuf,
                                                  float* __restrict__ ubuf) {
  const int e = threadIdx.x;
  const int f = blockIdx.x % FDIM;
  const int bh = blockIdx.x / FDIM;
  size_t base = ((size_t)bh * NCH * FDIM + f) * DV + e;
  float run = 0.f;
  for (int c = 0; c < NCH; c++) {
    size_t off = base + (size_t)c * FDIM * DV;
    float t = Sbuf[off]; Sbuf[off] = run; run += t;
  }
  if (e == 0) {
    size_t bu = (size_t)bh * NCH * FDIM + f;
    float ru = 0.f;
    for (int c = 0; c < NCH; c++) {
      float t = ubuf[bu + (size_t)c * FDIM];
      ubuf[bu + (size_t)c * FDIM] = ru; ru += t;
    }
  }
}

// ---------------------------------------------------------------------------
// Pass 3: per-(b,h,chunk) outputs.
//   intra: A_ij = 1 + s/4 + s^2/32 (s = q_i . k_j), causal, + row-sum -> den
//   inter: qf_i^T P (P = exclusive chunk-prefix state, staged in 32-row tiles)
//   y_i = num_i / (den_i + eps), fp32 out (b, l, h*64+e).
// 2 threads per i; each owns a 32-wide e-half.
// ---------------------------------------------------------------------------
__global__ __launch_bounds__(256) void attn_out(
    const float* __restrict__ qbuf, const float* __restrict__ kbuf,
    const float* __restrict__ vbuf, const float* __restrict__ Sbuf,
    const float* __restrict__ ubuf, float* __restrict__ ybuf) {
  const int c = blockIdx.x, bh = blockIdx.y;
  const int b = bh >> 4, h = bh & 15;
  __shared__ float qs[CHUNK][17];   // +1 pad: conflict-free qs[i][a] gathers
  __shared__ float ks2[CHUNK][17];
  __shared__ float vs[CHUNK][DV];
  __shared__ float Pt[32][DV];
  __shared__ float us[FDIM];
  const int tid = threadIdx.x;
  const int row0 = b * LSEQ + c * CHUNK;
  for (int idx = tid; idx < CHUNK * DQK; idx += 256) {
    int i = idx >> 4, d = idx & 15;
    qs[i][d] = qbuf[(size_t)(row0 + i) * (NH * DQK) + h * DQK + d];
    ks2[i][d] = kbuf[(size_t)(row0 + i) * (NH * DQK) + h * DQK + d];
  }
  for (int idx = tid; idx < CHUNK * DV; idx += 256) {
    int i = idx >> 6, d = idx & 63;
    vs[i][d] = vbuf[(size_t)(row0 + i) * (NH * DV) + h * DV + d];
  }
  for (int idx = tid; idx < FDIM; idx += 256)
    us[idx] = ubuf[((size_t)bh * NCH + c) * FDIM + idx];
  __syncthreads();

  const int i = tid >> 1;
  const int eh = (tid & 1) * 32;
  float q[DQK];
#pragma unroll
  for (int d = 0; d < DQK; d++) q[d] = qs[i][d];
  float4 acc[8];
#pragma unroll
  for (int r = 0; r < 8; r++) acc[r] = make_float4(0.f, 0.f, 0.f, 0.f);
  float den = 1e-12f;

  // intra-chunk (uniform j loop; causal via predicate -> no wave divergence)
  for (int j = 0; j < CHUNK; j++) {
    float s = 0.f;
#pragma unroll
    for (int d = 0; d < DQK; d++) s += q[d] * ks2[j][d];
    float aij = (j <= i) ? (1.0f + 0.25f * s + 0.03125f * s * s) : 0.0f;
    den += aij;
    const float4* vr = (const float4*)&vs[j][eh];
#pragma unroll
    for (int r = 0; r < 8; r++) {
      float4 vv = vr[r];
      acc[r].x += aij * vv.x; acc[r].y += aij * vv.y;
      acc[r].z += aij * vv.z; acc[r].w += aij * vv.w;
    }
  }

  // inter-chunk: stream P through LDS in 32-row tiles; fold den-inter in too
  for (int f0 = 0; f0 < FDIM; f0 += 32) {
    const int nr = min(32, FDIM - f0);
    __syncthreads();
    for (int idx = tid; idx < nr * DV; idx += 256) {
      int r = idx >> 6, e = idx & 63;
      Pt[r][e] = Sbuf[(((size_t)bh * NCH + c) * FDIM + f0 + r) * DV + e];
    }
    __syncthreads();
    for (int r = 0; r < nr; r++) {
      const int f = f0 + r;  // wave-uniform
      float qf;
      if (f == 0) qf = 1.0f;
      else if (f < 17) qf = 0.5f * qs[i][f - 1];
      else { int ix = f - 17; qf = C2 * qs[i][ix >> 4] * qs[i][ix & 15]; }
      den += qf * us[f];
      const float4* pr = (const float4*)&Pt[r][eh];
#pragma unroll
      for (int rr = 0; rr < 8; rr++) {
        float4 pv = pr[rr];
        acc[rr].x += qf * pv.x; acc[rr].y += qf * pv.y;
        acc[rr].z += qf * pv.z; acc[rr].w += qf * pv.w;
      }
    }
  }

  const float invd = 1.0f / den;
  float* yo = ybuf + (size_t)(row0 + i) * (NH * DV) + h * DV + eh;
#pragma unroll
  for (int rr = 0; rr < 8; rr++) {
    float4 st = make_float4(acc[rr].x * invd, acc[rr].y * invd,
                            acc[rr].z * invd, acc[rr].w * invd);
    ((float4*)yo)[rr] = st;
  }
}

// ---------------------------------------------------------------------------
extern "C" void kernel_launch(void* const* d_in, const int* in_sizes, int n_in,
                              void* d_out, int out_size, void* d_ws, size_t ws_size,
                              hipStream_t stream) {
  const float* hs = (const float*)d_in[0];
  const float* Wq = (const float*)d_in[1];
  const float* Wk = (const float*)d_in[2];
  const float* Wv = (const float*)d_in[3];
  const float* Wo = (const float*)d_in[4];
  float* out = (float*)d_out;

  // workspace layout (fp32): ~76 MB total
  float* qb = (float*)d_ws;                              // 4096*256
  float* kb = qb + (size_t)ROWS * (NH * DQK);            // 4096*256
  float* vb = kb + (size_t)ROWS * (NH * DQK);            // 4096*1024
  float* Sb = vb + (size_t)ROWS * (NH * DV);             // 32*16*273*64
  float* ub = Sb + (size_t)BATCH * NH * NCH * FDIM * DV; // 32*16*273
  float* yb = ub + (size_t)BATCH * NH * NCH * FDIM;      // 4096*1024

  // projections
  gemm_f32<<<dim3(4, ROWS / 64), 256, 0, stream>>>(hs, Wq, qb, ROWS, NH * DQK, DMODEL);
  gemm_f32<<<dim3(4, ROWS / 64), 256, 0, stream>>>(hs, Wk, kb, ROWS, NH * DQK, DMODEL);
  gemm_f32<<<dim3(16, ROWS / 64), 256, 0, stream>>>(hs, Wv, vb, ROWS, NH * DV, DMODEL);
  // chunked causal linear attention
  chunk_sums<<<dim3(NCH, BATCH * NH), 256, 0, stream>>>(kb, vb, Sb, ub);
  prefix_scan<<<dim3(BATCH * NH * FDIM), 64, 0, stream>>>(Sb, ub);
  attn_out<<<dim3(NCH, BATCH * NH), 256, 0, stream>>>(qb, kb, vb, Sb, ub, yb);
  // output projection
  gemm_f32<<<dim3(16, ROWS / 64), 256, 0, stream>>>(yb, Wo, out, ROWS, DMODEL, DMODEL);
}

// Round 3
// 408.817 us; speedup vs baseline: 1.5736x; 1.5736x over previous
//
#include <hip/hip_runtime.h>
#include <hip/hip_bf16.h>

// Problem constants
#define BATCH 2
#define LSEQ 2048
#define DMODEL 1024
#define NH 16
#define DQK 16
#define DV 64
#define FDIM 273            // 1 + 16 + 256
#define CHUNK 128
#define NCH (LSEQ / CHUNK)  // 16 chunks per batch row
#define ROWS (BATCH * LSEQ) // 4096
#define C2 0.17677669529663687f  // 1/(4*sqrt(2))

typedef short bf16x8 __attribute__((ext_vector_type(8)));
typedef float f32x4 __attribute__((ext_vector_type(4)));

__device__ __forceinline__ unsigned short f2bf(float f) {
  __hip_bfloat16 h = __float2bfloat16(f);
  unsigned short u; __builtin_memcpy(&u, &h, 2); return u;
}

// ---------------------------------------------------------------------------
// fp32 -> bf16 elementwise cast (float4 / ushort4 vectorized)
// ---------------------------------------------------------------------------
__global__ __launch_bounds__(256) void cast4(const float* __restrict__ in,
                                             unsigned short* __restrict__ out, int n4) {
  int i = blockIdx.x * 256 + threadIdx.x;
  if (i >= n4) return;
  float4 v = ((const float4*)in)[i];
  ushort4 o = {f2bf(v.x), f2bf(v.y), f2bf(v.z), f2bf(v.w)};
  ((ushort4*)out)[i] = o;
}

// ---------------------------------------------------------------------------
// W (KxN fp32, row-major) -> Wt (NxK bf16, row-major).  32x32 LDS tile.
// ---------------------------------------------------------------------------
__global__ __launch_bounds__(256) void transpose_cast(
    const float* __restrict__ W, unsigned short* __restrict__ Wt, int K, int N) {
  __shared__ float t[32][33];
  const int kb = blockIdx.y * 32, nb = blockIdx.x * 32;
  const int tx = threadIdx.x & 31, ty4 = (threadIdx.x >> 5) * 4;
#pragma unroll
  for (int r = 0; r < 4; r++)
    t[ty4 + r][tx] = W[(size_t)(kb + ty4 + r) * N + nb + tx];
  __syncthreads();
#pragma unroll
  for (int r = 0; r < 4; r++)
    Wt[(size_t)(nb + ty4 + r) * K + kb + tx] = f2bf(t[tx][ty4 + r]);
}

// ---------------------------------------------------------------------------
// MFMA GEMM (m97 pattern): C(MxN fp32) = A(MxK bf16) @ Bt(NxK bf16)^T.
// 128x128 tile, BK=32, 256 threads = 4 waves, each wave a 64x64 quadrant
// (4x4 grid of 16x16x32 bf16 MFMA).  global_load_lds width=16 stages both
// tiles in fragment-major chunk layout: chunk(cb, kh, m) = cb*64 + kh*16 + m
// holds X[cb*16+m][kh*8 .. +7].  Fragment read = contiguous 1 KB per wave.
// ---------------------------------------------------------------------------
__global__ __launch_bounds__(256) void gemm_mfma(
    const unsigned short* __restrict__ A, const unsigned short* __restrict__ Bt,
    float* __restrict__ C, int M, int N, int K) {
  __shared__ unsigned short As[512 * 8];  // 8 KB
  __shared__ unsigned short Bs[512 * 8];  // 8 KB
  const int tid = threadIdx.x;
  const int bm = blockIdx.y * 128, bn = blockIdx.x * 128;
  const int lane = tid & 63;
  const int w = tid >> 6;
  const int qr = (w >> 1) * 64, qc = (w & 1) * 64;  // wave quadrant origin
  f32x4 acc[4][4] = {};

  for (int k0 = 0; k0 < K; k0 += 32) {
    // stage A-tile (chunks 0..511) and B-tile (512..1023); 4 chunks/thread
#pragma unroll
    for (int j = 0; j < 4; ++j) {
      int c = j * 256 + tid;
      int cc = c & 511;
      int row = ((cc >> 6) << 4) + (cc & 15);
      int kh = (cc >> 4) & 3;
      const unsigned short* gp;
      unsigned short* lp;
      if (c < 512) { gp = A  + (size_t)(bm + row) * K + k0 + kh * 8; lp = As + cc * 8; }
      else         { gp = Bt + (size_t)(bn + row) * K + k0 + kh * 8; lp = Bs + cc * 8; }
      __builtin_amdgcn_global_load_lds(
          (const __attribute__((address_space(1))) unsigned int*)(const void*)gp,
          (__attribute__((address_space(3))) unsigned int*)lp, 16, 0, 0);
    }
    __syncthreads();
    bf16x8 a[4], b[4];
#pragma unroll
    for (int i = 0; i < 4; ++i) {
      a[i] = *(const bf16x8*)(As + ((qr >> 4) + i) * 512 + lane * 8);
      b[i] = *(const bf16x8*)(Bs + ((qc >> 4) + i) * 512 + lane * 8);
    }
#pragma unroll
    for (int i = 0; i < 4; ++i)
#pragma unroll
      for (int jj = 0; jj < 4; ++jj)
        acc[i][jj] = __builtin_amdgcn_mfma_f32_16x16x32_bf16(a[i], b[jj], acc[i][jj], 0, 0, 0);
    __syncthreads();
  }

  // epilogue: C/D layout col = lane&15, row = (lane>>4)*4 + reg
  const int cn = lane & 15, r0 = (lane >> 4) * 4;
#pragma unroll
  for (int i = 0; i < 4; ++i)
#pragma unroll
    for (int jj = 0; jj < 4; ++jj) {
      size_t base = (size_t)(bm + qr + i * 16 + r0) * N + bn + qc + jj * 16 + cn;
#pragma unroll
      for (int r = 0; r < 4; ++r) C[base + (size_t)r * N] = acc[i][jj][r];
    }
}

// ---------------------------------------------------------------------------
// Pass 1: per-(b,h,chunk) sums  S_c[f][e] = sum_i kf_i[f] * v_i[e],
//         u_c[f] = sum_i kf_i[f].  320 threads: all 273 features in ONE pass.
// ---------------------------------------------------------------------------
__global__ __launch_bounds__(320) void chunk_sums(
    const float* __restrict__ kbuf, const float* __restrict__ vbuf,
    float* __restrict__ Sbuf, float* __restrict__ ubuf) {
  const int c = blockIdx.x, bh = blockIdx.y;
  const int b = bh >> 4, h = bh & 15;
  __shared__ float ks[CHUNK][DQK];
  __shared__ float vs[CHUNK][DV];
  const int tid = threadIdx.x;
  const int row0 = b * LSEQ + c * CHUNK;
  for (int idx = tid; idx < CHUNK * DQK; idx += 320) {
    int i = idx >> 4, d = idx & 15;
    ks[i][d] = kbuf[(size_t)(row0 + i) * (NH * DQK) + h * DQK + d];
  }
  for (int idx = tid; idx < CHUNK * DV; idx += 320) {
    int i = idx >> 6, d = idx & 63;
    vs[i][d] = vbuf[(size_t)(row0 + i) * (NH * DV) + h * DV + d];
  }
  __syncthreads();
  const int f = tid;
  if (f < FDIM) {
    float4 acc[16];
#pragma unroll
    for (int r = 0; r < 16; r++) acc[r] = make_float4(0.f, 0.f, 0.f, 0.f);
    float usum = 0.f;
    const int a1 = (f == 0) ? 0 : ((f < 17) ? (f - 1) : ((f - 17) >> 4));
    const int b1 = (f >= 17) ? ((f - 17) & 15) : 0;
    for (int i = 0; i < CHUNK; i++) {
      float kf;
      if (f == 0) kf = 1.0f;
      else if (f < 17) kf = 0.5f * ks[i][a1];
      else kf = C2 * ks[i][a1] * ks[i][b1];
      usum += kf;
      const float4* vr = (const float4*)&vs[i][0];
#pragma unroll
      for (int r = 0; r < 16; r++) {
        float4 vv = vr[r];
        acc[r].x += kf * vv.x; acc[r].y += kf * vv.y;
        acc[r].z += kf * vv.z; acc[r].w += kf * vv.w;
      }
    }
    float* Sout = Sbuf + (((size_t)bh * NCH + c) * FDIM + f) * DV;
#pragma unroll
    for (int r = 0; r < 16; r++) ((float4*)Sout)[r] = acc[r];
    ubuf[((size_t)bh * NCH + c) * FDIM + f] = usum;
  }
}

// ---------------------------------------------------------------------------
// Pass 2: in-place exclusive prefix over chunks for S and u.
// ---------------------------------------------------------------------------
__global__ __launch_bounds__(64) void prefix_scan(float* __restrict__ Sbuf,
                                                  float* __restrict__ ubuf) {
  const int e = threadIdx.x;
  const int f = blockIdx.x % FDIM;
  const int bh = blockIdx.x / FDIM;
  size_t base = ((size_t)bh * NCH * FDIM + f) * DV + e;
  float run = 0.f;
  for (int c = 0; c < NCH; c++) {
    size_t off = base + (size_t)c * FDIM * DV;
    float t = Sbuf[off]; Sbuf[off] = run; run += t;
  }
  if (e == 0) {
    size_t bu = (size_t)bh * NCH * FDIM + f;
    float ru = 0.f;
    for (int c = 0; c < NCH; c++) {
      float t = ubuf[bu + (size_t)c * FDIM];
      ubuf[bu + (size_t)c * FDIM] = ru; ru += t;
    }
  }
}

// ---------------------------------------------------------------------------
// Pass 3: per-(b,h,chunk) outputs -> bf16 y.
//   intra: A_ij = 1 + s/4 + s^2/32 (s = q_i . k_j), causal, + row-sum -> den
//   inter: qf_i^T P (P = exclusive chunk-prefix state, 32-row LDS tiles)
// 2 threads per row i; each owns a 32-wide e-half.  ks2 rows padded to 20
// floats (80 B) so the k-row broadcast reads are 4x ds_read_b128.
// ---------------------------------------------------------------------------
__global__ __launch_bounds__(256) void attn_out(
    const float* __restrict__ qbuf, const float* __restrict__ kbuf,
    const float* __restrict__ vbuf, const float* __restrict__ Sbuf,
    const float* __restrict__ ubuf, unsigned short* __restrict__ ybuf) {
  const int c = blockIdx.x, bh = blockIdx.y;
  const int b = bh >> 4, h = bh & 15;
  __shared__ float qs[CHUNK][17];   // scalar gathers: 17-stride = conflict-free
  __shared__ float ks2[CHUNK][20];  // b128-aligned rows for broadcast reads
  __shared__ float vs[CHUNK][DV];
  __shared__ float Pt[32][DV];
  __shared__ float us[FDIM];
  const int tid = threadIdx.x;
  const int row0 = b * LSEQ + c * CHUNK;
  for (int idx = tid; idx < CHUNK * DQK; idx += 256) {
    int i = idx >> 4, d = idx & 15;
    qs[i][d] = qbuf[(size_t)(row0 + i) * (NH * DQK) + h * DQK + d];
    ks2[i][d] = kbuf[(size_t)(row0 + i) * (NH * DQK) + h * DQK + d];
  }
  for (int idx = tid; idx < CHUNK * DV; idx += 256) {
    int i = idx >> 6, d = idx & 63;
    vs[i][d] = vbuf[(size_t)(row0 + i) * (NH * DV) + h * DV + d];
  }
  for (int idx = tid; idx < FDIM; idx += 256)
    us[idx] = ubuf[((size_t)bh * NCH + c) * FDIM + idx];
  __syncthreads();

  const int i = tid >> 1;
  const int eh = (tid & 1) * 32;
  float4 q4[4];
#pragma unroll
  for (int d = 0; d < 4; d++)
    q4[d] = make_float4(qs[i][d * 4], qs[i][d * 4 + 1], qs[i][d * 4 + 2], qs[i][d * 4 + 3]);
  float4 acc[8];
#pragma unroll
  for (int r = 0; r < 8; r++) acc[r] = make_float4(0.f, 0.f, 0.f, 0.f);
  float den = 1e-12f;

  // intra-chunk (uniform j loop; causal via predicate)
  for (int j = 0; j < CHUNK; j++) {
    float4 k0 = *(const float4*)&ks2[j][0];
    float4 k1 = *(const float4*)&ks2[j][4];
    float4 k2 = *(const float4*)&ks2[j][8];
    float4 k3 = *(const float4*)&ks2[j][12];
    float s = q4[0].x * k0.x + q4[0].y * k0.y + q4[0].z * k0.z + q4[0].w * k0.w
            + q4[1].x * k1.x + q4[1].y * k1.y + q4[1].z * k1.z + q4[1].w * k1.w
            + q4[2].x * k2.x + q4[2].y * k2.y + q4[2].z * k2.z + q4[2].w * k2.w
            + q4[3].x * k3.x + q4[3].y * k3.y + q4[3].z * k3.z + q4[3].w * k3.w;
    float aij = (j <= i) ? (1.0f + 0.25f * s + 0.03125f * s * s) : 0.0f;
    den += aij;
    const float4* vr = (const float4*)&vs[j][eh];
#pragma unroll
    for (int r = 0; r < 8; r++) {
      float4 vv = vr[r];
      acc[r].x += aij * vv.x; acc[r].y += aij * vv.y;
      acc[r].z += aij * vv.z; acc[r].w += aij * vv.w;
    }
  }

  // inter-chunk: stream P through LDS in 32-row tiles
  for (int f0 = 0; f0 < FDIM; f0 += 32) {
    const int nr = min(32, FDIM - f0);
    __syncthreads();
    for (int idx = tid; idx < nr * DV; idx += 256) {
      int r = idx >> 6, e = idx & 63;
      Pt[r][e] = Sbuf[(((size_t)bh * NCH + c) * FDIM + f0 + r) * DV + e];
    }
    __syncthreads();
    for (int r = 0; r < nr; r++) {
      const int f = f0 + r;  // wave-uniform
      float qf;
      if (f == 0) qf = 1.0f;
      else if (f < 17) qf = 0.5f * qs[i][f - 1];
      else { int ix = f - 17; qf = C2 * qs[i][ix >> 4] * qs[i][ix & 15]; }
      den += qf * us[f];
      const float4* pr = (const float4*)&Pt[r][eh];
#pragma unroll
      for (int rr = 0; rr < 8; rr++) {
        float4 pv = pr[rr];
        acc[rr].x += qf * pv.x; acc[rr].y += qf * pv.y;
        acc[rr].z += qf * pv.z; acc[rr].w += qf * pv.w;
      }
    }
  }

  const float invd = 1.0f / den;
  unsigned short* yo = ybuf + (size_t)(row0 + i) * (NH * DV) + h * DV + eh;
#pragma unroll
  for (int rr = 0; rr < 8; rr++) {
    ushort4 st = {f2bf(acc[rr].x * invd), f2bf(acc[rr].y * invd),
                  f2bf(acc[rr].z * invd), f2bf(acc[rr].w * invd)};
    ((ushort4*)yo)[rr] = st;
  }
}

// ---------------------------------------------------------------------------
extern "C" void kernel_launch(void* const* d_in, const int* in_sizes, int n_in,
                              void* d_out, int out_size, void* d_ws, size_t ws_size,
                              hipStream_t stream) {
  const float* hs = (const float*)d_in[0];
  const float* Wq = (const float*)d_in[1];
  const float* Wk = (const float*)d_in[2];
  const float* Wv = (const float*)d_in[3];
  const float* Wo = (const float*)d_in[4];
  float* out = (float*)d_out;

  // workspace layout (~72 MB)
  float* qb = (float*)d_ws;                               // 4096*256 f32
  float* kb = qb + (size_t)ROWS * (NH * DQK);             // 4096*256 f32
  float* vb = kb + (size_t)ROWS * (NH * DQK);             // 4096*1024 f32
  float* Sb = vb + (size_t)ROWS * (NH * DV);              // 512*273*64 f32
  float* ub = Sb + (size_t)BATCH * NH * NCH * FDIM * DV;  // 512*273 f32
  unsigned short* hsb = (unsigned short*)(ub + (size_t)BATCH * NH * NCH * FDIM); // 4M bf16
  unsigned short* yb  = hsb;  // alias: hsb dead after proj GEMMs, yb written later
  unsigned short* wqt = hsb + (size_t)ROWS * DMODEL;      // 256x1024 bf16
  unsigned short* wkt = wqt + (size_t)(NH * DQK) * DMODEL;
  unsigned short* wvt = wkt + (size_t)(NH * DQK) * DMODEL; // 1024x1024 bf16
  unsigned short* wot = wvt + (size_t)(NH * DV) * DMODEL;  // 1024x1024 bf16

  // casts / transposes
  cast4<<<dim3((ROWS * DMODEL / 4 + 255) / 256), 256, 0, stream>>>(hs, hsb, ROWS * DMODEL / 4);
  transpose_cast<<<dim3((NH * DQK) / 32, DMODEL / 32), 256, 0, stream>>>(Wq, wqt, DMODEL, NH * DQK);
  transpose_cast<<<dim3((NH * DQK) / 32, DMODEL / 32), 256, 0, stream>>>(Wk, wkt, DMODEL, NH * DQK);
  transpose_cast<<<dim3((NH * DV) / 32, DMODEL / 32), 256, 0, stream>>>(Wv, wvt, DMODEL, NH * DV);
  transpose_cast<<<dim3(DMODEL / 32, DMODEL / 32), 256, 0, stream>>>(Wo, wot, DMODEL, DMODEL);

  // projections (MFMA)
  gemm_mfma<<<dim3((NH * DQK) / 128, ROWS / 128), 256, 0, stream>>>(hsb, wqt, qb, ROWS, NH * DQK, DMODEL);
  gemm_mfma<<<dim3((NH * DQK) / 128, ROWS / 128), 256, 0, stream>>>(hsb, wkt, kb, ROWS, NH * DQK, DMODEL);
  gemm_mfma<<<dim3((NH * DV) / 128, ROWS / 128), 256, 0, stream>>>(hsb, wvt, vb, ROWS, NH * DV, DMODEL);

  // chunked causal linear attention
  chunk_sums<<<dim3(NCH, BATCH * NH), 320, 0, stream>>>(kb, vb, Sb, ub);
  prefix_scan<<<dim3(BATCH * NH * FDIM), 64, 0, stream>>>(Sb, ub);
  attn_out<<<dim3(NCH, BATCH * NH), 256, 0, stream>>>(qb, kb, vb, Sb, ub, yb);

  // output projection (MFMA): out = yb @ Wo
  gemm_mfma<<<dim3(DMODEL / 128, ROWS / 128), 256, 0, stream>>>(yb, wot, out, ROWS, DMODEL, DMODEL);
}

// Round 4
// 305.546 us; speedup vs baseline: 2.1054x; 1.3380x over previous
//
#include <hip/hip_runtime.h>
#include <hip/hip_bf16.h>

// Problem constants
#define BATCH 2
#define LSEQ 2048
#define DMODEL 1024
#define NH 16
#define DQK 16
#define DV 64
#define FDIM 273            // 1 + 16 + 256
#define CHUNK 128
#define NCH (LSEQ / CHUNK)  // 16 chunks per batch row
#define ROWS (BATCH * LSEQ) // 4096
#define C2 0.17677669529663687f  // 1/(4*sqrt(2))

typedef short bf16x8 __attribute__((ext_vector_type(8)));
typedef float f32x4 __attribute__((ext_vector_type(4)));

__device__ __forceinline__ unsigned short f2bf(float f) {
  __hip_bfloat16 h = __float2bfloat16(f);
  unsigned short u; __builtin_memcpy(&u, &h, 2); return u;
}

// ---------------------------------------------------------------------------
// fp32 -> bf16 elementwise cast (float4 / ushort4 vectorized)
// ---------------------------------------------------------------------------
__global__ __launch_bounds__(256) void cast4(const float* __restrict__ in,
                                             unsigned short* __restrict__ out, int n4) {
  int i = blockIdx.x * 256 + threadIdx.x;
  if (i >= n4) return;
  float4 v = ((const float4*)in)[i];
  ushort4 o = {f2bf(v.x), f2bf(v.y), f2bf(v.z), f2bf(v.w)};
  ((ushort4*)out)[i] = o;
}

// ---------------------------------------------------------------------------
// W (KxN fp32, row-major) -> Wt (NxK bf16, row-major).  32x32 LDS tile.
// ---------------------------------------------------------------------------
__global__ __launch_bounds__(256) void transpose_cast(
    const float* __restrict__ W, unsigned short* __restrict__ Wt, int K, int N) {
  __shared__ float t[32][33];
  const int kb = blockIdx.y * 32, nb = blockIdx.x * 32;
  const int tx = threadIdx.x & 31, ty4 = (threadIdx.x >> 5) * 4;
#pragma unroll
  for (int r = 0; r < 4; r++)
    t[ty4 + r][tx] = W[(size_t)(kb + ty4 + r) * N + nb + tx];
  __syncthreads();
#pragma unroll
  for (int r = 0; r < 4; r++)
    Wt[(size_t)(nb + ty4 + r) * K + kb + tx] = f2bf(t[tx][ty4 + r]);
}

// ---------------------------------------------------------------------------
// MFMA GEMM (m97 pattern): C(MxN fp32) = A(MxK bf16) @ Bt(NxK bf16)^T.
// 128x128 tile, BK=32, 256 threads = 4 waves, each wave a 64x64 quadrant.
// ---------------------------------------------------------------------------
__global__ __launch_bounds__(256) void gemm_mfma(
    const unsigned short* __restrict__ A, const unsigned short* __restrict__ Bt,
    float* __restrict__ C, int M, int N, int K) {
  __shared__ unsigned short As[512 * 8];
  __shared__ unsigned short Bs[512 * 8];
  const int tid = threadIdx.x;
  const int bm = blockIdx.y * 128, bn = blockIdx.x * 128;
  const int lane = tid & 63;
  const int w = tid >> 6;
  const int qr = (w >> 1) * 64, qc = (w & 1) * 64;
  f32x4 acc[4][4] = {};

  for (int k0 = 0; k0 < K; k0 += 32) {
#pragma unroll
    for (int j = 0; j < 4; ++j) {
      int c = j * 256 + tid;
      int cc = c & 511;
      int row = ((cc >> 6) << 4) + (cc & 15);
      int kh = (cc >> 4) & 3;
      const unsigned short* gp;
      unsigned short* lp;
      if (c < 512) { gp = A  + (size_t)(bm + row) * K + k0 + kh * 8; lp = As + cc * 8; }
      else         { gp = Bt + (size_t)(bn + row) * K + k0 + kh * 8; lp = Bs + cc * 8; }
      __builtin_amdgcn_global_load_lds(
          (const __attribute__((address_space(1))) unsigned int*)(const void*)gp,
          (__attribute__((address_space(3))) unsigned int*)lp, 16, 0, 0);
    }
    __syncthreads();
    bf16x8 a[4], b[4];
#pragma unroll
    for (int i = 0; i < 4; ++i) {
      a[i] = *(const bf16x8*)(As + ((qr >> 4) + i) * 512 + lane * 8);
      b[i] = *(const bf16x8*)(Bs + ((qc >> 4) + i) * 512 + lane * 8);
    }
#pragma unroll
    for (int i = 0; i < 4; ++i)
#pragma unroll
      for (int jj = 0; jj < 4; ++jj)
        acc[i][jj] = __builtin_amdgcn_mfma_f32_16x16x32_bf16(a[i], b[jj], acc[i][jj], 0, 0, 0);
    __syncthreads();
  }
  const int cn = lane & 15, r0 = (lane >> 4) * 4;
#pragma unroll
  for (int i = 0; i < 4; ++i)
#pragma unroll
    for (int jj = 0; jj < 4; ++jj) {
      size_t base = (size_t)(bm + qr + i * 16 + r0) * N + bn + qc + jj * 16 + cn;
#pragma unroll
      for (int r = 0; r < 4; ++r) C[base + (size_t)r * N] = acc[i][jj][r];
    }
}

// ---------------------------------------------------------------------------
// Pass 1: per-(b,h,chunk) sums  S_c[f][e] = sum_i kf_i[f] * v_i[e],
//         u_c[f] = sum_i kf_i[f].  320 threads, k read from merged qk buffer.
// ---------------------------------------------------------------------------
__global__ __launch_bounds__(320) void chunk_sums(
    const float* __restrict__ qkb, const float* __restrict__ vbuf,
    float* __restrict__ Sbuf, float* __restrict__ ubuf) {
  const int c = blockIdx.x, bh = blockIdx.y;
  const int b = bh >> 4, h = bh & 15;
  __shared__ float ks[CHUNK][DQK];
  __shared__ float vs[CHUNK][DV];
  const int tid = threadIdx.x;
  const int row0 = b * LSEQ + c * CHUNK;
  for (int idx = tid; idx < CHUNK * DQK; idx += 320) {
    int i = idx >> 4, d = idx & 15;
    ks[i][d] = qkb[(size_t)(row0 + i) * 512 + 256 + h * DQK + d];
  }
  for (int idx = tid; idx < CHUNK * DV; idx += 320) {
    int i = idx >> 6, d = idx & 63;
    vs[i][d] = vbuf[(size_t)(row0 + i) * (NH * DV) + h * DV + d];
  }
  __syncthreads();
  const int f = tid;
  if (f < FDIM) {
    float4 acc[16];
#pragma unroll
    for (int r = 0; r < 16; r++) acc[r] = make_float4(0.f, 0.f, 0.f, 0.f);
    float usum = 0.f;
    const int a1 = (f == 0) ? 0 : ((f < 17) ? (f - 1) : ((f - 17) >> 4));
    const int b1 = (f >= 17) ? ((f - 17) & 15) : 0;
    for (int i = 0; i < CHUNK; i++) {
      float kf;
      if (f == 0) kf = 1.0f;
      else if (f < 17) kf = 0.5f * ks[i][a1];
      else kf = C2 * ks[i][a1] * ks[i][b1];
      usum += kf;
      const float4* vr = (const float4*)&vs[i][0];
#pragma unroll
      for (int r = 0; r < 16; r++) {
        float4 vv = vr[r];
        acc[r].x += kf * vv.x; acc[r].y += kf * vv.y;
        acc[r].z += kf * vv.z; acc[r].w += kf * vv.w;
      }
    }
    float* Sout = Sbuf + (((size_t)bh * NCH + c) * FDIM + f) * DV;
#pragma unroll
    for (int r = 0; r < 16; r++) ((float4*)Sout)[r] = acc[r];
    ubuf[((size_t)bh * NCH + c) * FDIM + f] = usum;
  }
}

// ---------------------------------------------------------------------------
// Pass 2: in-place exclusive prefix over chunks for S and u.
// ---------------------------------------------------------------------------
__global__ __launch_bounds__(64) void prefix_scan(float* __restrict__ Sbuf,
                                                  float* __restrict__ ubuf) {
  const int e = threadIdx.x;
  const int f = blockIdx.x % FDIM;
  const int bh = blockIdx.x / FDIM;
  size_t base = ((size_t)bh * NCH * FDIM + f) * DV + e;
  float run = 0.f;
  for (int c = 0; c < NCH; c++) {
    size_t off = base + (size_t)c * FDIM * DV;
    float t = Sbuf[off]; Sbuf[off] = run; run += t;
  }
  if (e == 0) {
    size_t bu = (size_t)bh * NCH * FDIM + f;
    float ru = 0.f;
    for (int c = 0; c < NCH; c++) {
      float t = ubuf[bu + (size_t)c * FDIM];
      ubuf[bu + (size_t)c * FDIM] = ru; ru += t;
    }
  }
}

// ---------------------------------------------------------------------------
// Pass 3 (MFMA): per-(b,h,chunk) outputs -> bf16 y.
//   S = Q·K^T (16x16x32 MFMA, K padded 16->32), A = poly(S) masked -> LDS
//   Y = A·[V|1]  (den via ones column)  then  Y += Qf·[P|u] in 9 k-tiles.
// All operands in fragment-major LDS layout: buf[tile*512 + lane*8] holds
// X[tile*16 + (lane&15)][(lane>>4)*8 .. +7]  (m97-verified fragment path).
// C/D layout: col=lane&15, row=(lane>>4)*4+reg.
// ---------------------------------------------------------------------------
__global__ __launch_bounds__(256) void attn_mfma(
    const float* __restrict__ qkb, const float* __restrict__ vbuf,
    const float* __restrict__ Sbuf, const float* __restrict__ ubuf,
    unsigned short* __restrict__ ybuf) {
  const int c = blockIdx.x, bh = blockIdx.y;
  const int b = bh >> 4, h = bh & 15;
  const int tid = threadIdx.x;
  const int lane = tid & 63, w = tid >> 6;
  const int row0 = b * LSEQ + c * CHUNK;

  __shared__ short Am[16384];   // 32 KB: phases 1-2: A-matrix; phase 3: Qf(0..4095)+Pp(4096..6655)
  __shared__ short QKV[10240];  // 20 KB: phase 1: Qb(0..4095), Kb(4096..8191); phase 2: Vp
  __shared__ float qsF[2048];   // 8 KB: q fp32 (for Qf generation)
  __shared__ float denL[128];

  // ---- stage qsF ----
  {
    int i = tid >> 1, d0 = (tid & 1) * 8;
    const float* src = qkb + (size_t)(row0 + i) * 512 + h * 16 + d0;
    float4 v0 = *(const float4*)src;
    float4 v1 = *(const float4*)(src + 4);
    *(float4*)&qsF[i * 16 + d0] = v0;
    *(float4*)&qsF[i * 16 + d0 + 4] = v1;
  }
  // ---- stage Qb, Kb (bf16, K padded to 32 with zeros) ----
  for (int t = tid; t < 1024; t += 256) {
    int isK = t >> 9;
    int tt = t & 511;
    int i = tt >> 2, kh = tt & 3;
    bf16x8 v8 = {0, 0, 0, 0, 0, 0, 0, 0};
    if (kh < 2) {
      const float* src = qkb + (size_t)(row0 + i) * 512 + isK * 256 + h * 16 + kh * 8;
      float4 a = *(const float4*)src;
      float4 bq = *(const float4*)(src + 4);
      v8[0] = (short)f2bf(a.x);  v8[1] = (short)f2bf(a.y);
      v8[2] = (short)f2bf(a.z);  v8[3] = (short)f2bf(a.w);
      v8[4] = (short)f2bf(bq.x); v8[5] = (short)f2bf(bq.y);
      v8[6] = (short)f2bf(bq.z); v8[7] = (short)f2bf(bq.w);
    }
    *(bf16x8*)(QKV + isK * 4096 + (i >> 4) * 512 + (kh * 16 + (i & 15)) * 8) = v8;
  }
  __syncthreads();

  // ---- phase 1: S = Q K^T -> poly+mask -> Am ----
  {
    bf16x8 aq[2];
#pragma unroll
    for (int mi = 0; mi < 2; mi++)
      aq[mi] = *(const bf16x8*)(QKV + (w * 2 + mi) * 512 + lane * 8);
    f32x4 S[2][8] = {};
#pragma unroll
    for (int nt = 0; nt < 8; nt++) {
      bf16x8 bk = *(const bf16x8*)(QKV + 4096 + nt * 512 + lane * 8);
#pragma unroll
      for (int mi = 0; mi < 2; mi++)
        S[mi][nt] = __builtin_amdgcn_mfma_f32_16x16x32_bf16(aq[mi], bk, S[mi][nt], 0, 0, 0);
    }
    const int cl = lane & 15, r0q = (lane >> 4) * 4;
#pragma unroll
    for (int mi = 0; mi < 2; mi++)
#pragma unroll
      for (int nt = 0; nt < 8; nt++)
#pragma unroll
        for (int reg = 0; reg < 4; reg++) {
          int i = (w * 2 + mi) * 16 + r0q + reg;
          int j = nt * 16 + cl;
          float s = S[mi][nt][reg];
          float aij = (j <= i) ? fmaf(s, fmaf(s, 0.03125f, 0.25f), 1.0f) : 0.0f;
          Am[((i >> 4) * 4 + (j >> 5)) * 512 + (((j >> 3) & 3) * 16 + (i & 15)) * 8 + (j & 7)] =
              (short)f2bf(aij);
        }
  }
  __syncthreads();

  // ---- stage Vp = [V | 1 | 0-pad] transposed (B-operand, N=80, K=128) ----
  for (int t = tid; t < 1280; t += 256) {
    int e, jg;
    if (t < 1024) { e = t & 63; jg = t >> 6; }
    else { int x = t - 1024; e = 64 + (x & 15); jg = x >> 4; }
    bf16x8 v8;
#pragma unroll
    for (int jj = 0; jj < 8; jj++) {
      float val;
      if (e < 64) val = vbuf[(size_t)(row0 + jg * 8 + jj) * (NH * DV) + h * DV + e];
      else val = (e == 64) ? 1.0f : 0.0f;
      v8[jj] = (short)f2bf(val);
    }
    *(bf16x8*)(QKV + ((e >> 4) * 4 + (jg >> 2)) * 512 + ((jg & 3) * 16 + (e & 15)) * 8) = v8;
  }
  __syncthreads();

  // ---- phase 2: Y = A · Vp ----
  f32x4 Y[2][5] = {};
#pragma unroll
  for (int kc = 0; kc < 4; kc++) {
    bf16x8 a2[2];
#pragma unroll
    for (int mi = 0; mi < 2; mi++)
      a2[mi] = *(const bf16x8*)(Am + ((w * 2 + mi) * 4 + kc) * 512 + lane * 8);
#pragma unroll
    for (int nt = 0; nt < 5; nt++) {
      bf16x8 b2 = *(const bf16x8*)(QKV + (nt * 4 + kc) * 512 + lane * 8);
#pragma unroll
      for (int mi = 0; mi < 2; mi++)
        Y[mi][nt] = __builtin_amdgcn_mfma_f32_16x16x32_bf16(a2[mi], b2, Y[mi][nt], 0, 0, 0);
    }
  }

  // ---- phase 3: Y += Qf · [P|u], 9 k-tiles of 32 features ----
  const size_t sbase = ((size_t)bh * NCH + c) * FDIM;
  for (int ft = 0; ft < 9; ft++) {
    const int f0 = ft * 32;
    __syncthreads();  // previous readers of Am region done
    // Qf tile (A-operand, M=128, K=32)
    for (int t = tid; t < 512; t += 256) {
      int i = t >> 2, fh = t & 3;
      bf16x8 v8;
#pragma unroll
      for (int e2 = 0; e2 < 8; e2++) {
        int f = f0 + fh * 8 + e2;
        float qf;
        if (f == 0) qf = 1.0f;
        else if (f < 17) qf = 0.5f * qsF[i * 16 + f - 1];
        else if (f < FDIM) {
          int ix = f - 17;
          qf = C2 * qsF[i * 16 + (ix >> 4)] * qsF[i * 16 + (ix & 15)];
        } else qf = 0.0f;
        v8[e2] = (short)f2bf(qf);
      }
      *(bf16x8*)(Am + (i >> 4) * 512 + (fh * 16 + (i & 15)) * 8) = v8;
    }
    // Pp tile (B-operand, N=80, K=32): P rows f0..f0+31 transposed + u col
    for (int t = tid; t < 320; t += 256) {
      int e, fg;
      if (t < 256) { e = t & 63; fg = t >> 6; }
      else { int x = t - 256; e = 64 + (x & 15); fg = x >> 4; }
      bf16x8 v8;
#pragma unroll
      for (int ff = 0; ff < 8; ff++) {
        int f = f0 + fg * 8 + ff;
        float val = 0.0f;
        if (f < FDIM) {
          if (e < 64) val = Sbuf[(sbase + f) * DV + e];
          else if (e == 64) val = ubuf[sbase + f];
        }
        v8[ff] = (short)f2bf(val);
      }
      *(bf16x8*)(Am + 4096 + (e >> 4) * 512 + (fg * 16 + (e & 15)) * 8) = v8;
    }
    __syncthreads();
    bf16x8 a3[2];
#pragma unroll
    for (int mi = 0; mi < 2; mi++)
      a3[mi] = *(const bf16x8*)(Am + (w * 2 + mi) * 512 + lane * 8);
#pragma unroll
    for (int nt = 0; nt < 5; nt++) {
      bf16x8 b3 = *(const bf16x8*)(Am + 4096 + nt * 512 + lane * 8);
#pragma unroll
      for (int mi = 0; mi < 2; mi++)
        Y[mi][nt] = __builtin_amdgcn_mfma_f32_16x16x32_bf16(a3[mi], b3, Y[mi][nt], 0, 0, 0);
    }
  }

  // ---- epilogue: den from ones column (nt=4, col 0), scale, store bf16 ----
  const int cl = lane & 15, r0q = (lane >> 4) * 4;
  if (cl == 0) {
#pragma unroll
    for (int mi = 0; mi < 2; mi++)
#pragma unroll
      for (int reg = 0; reg < 4; reg++)
        denL[(w * 2 + mi) * 16 + r0q + reg] = Y[mi][4][reg];
  }
  __syncthreads();
#pragma unroll
  for (int mi = 0; mi < 2; mi++) {
    float invd[4];
#pragma unroll
    for (int reg = 0; reg < 4; reg++)
      invd[reg] = 1.0f / (denL[(w * 2 + mi) * 16 + r0q + reg] + 1e-12f);
#pragma unroll
    for (int nt = 0; nt < 4; nt++)
#pragma unroll
      for (int reg = 0; reg < 4; reg++) {
        int i = (w * 2 + mi) * 16 + r0q + reg;
        int e = nt * 16 + cl;
        ybuf[(size_t)(row0 + i) * (NH * DV) + h * DV + e] =
            f2bf(Y[mi][nt][reg] * invd[reg]);
      }
  }
}

// ---------------------------------------------------------------------------
extern "C" void kernel_launch(void* const* d_in, const int* in_sizes, int n_in,
                              void* d_out, int out_size, void* d_ws, size_t ws_size,
                              hipStream_t stream) {
  const float* hs = (const float*)d_in[0];
  const float* Wq = (const float*)d_in[1];
  const float* Wk = (const float*)d_in[2];
  const float* Wv = (const float*)d_in[3];
  const float* Wo = (const float*)d_in[4];
  float* out = (float*)d_out;

  // workspace layout (~73 MB)
  float* qkb = (float*)d_ws;                              // 4096 x 512 f32 (q|k)
  float* vb  = qkb + (size_t)ROWS * 512;                  // 4096 x 1024 f32
  float* Sb  = vb + (size_t)ROWS * (NH * DV);             // 512*273*64 f32
  float* ub  = Sb + (size_t)BATCH * NH * NCH * FDIM * DV; // 512*273 f32
  unsigned short* hsb = (unsigned short*)(ub + (size_t)BATCH * NH * NCH * FDIM);
  unsigned short* yb  = hsb;  // alias: hsb dead after projection GEMMs
  unsigned short* wqt = hsb + (size_t)ROWS * DMODEL;      // 256x1024 bf16
  unsigned short* wkt = wqt + (size_t)(NH * DQK) * DMODEL; // (adjacent -> [Wq|Wk]^T)
  unsigned short* wvt = wkt + (size_t)(NH * DQK) * DMODEL; // 1024x1024 bf16
  unsigned short* wot = wvt + (size_t)(NH * DV) * DMODEL;  // 1024x1024 bf16

  // casts / transposes
  cast4<<<dim3((ROWS * DMODEL / 4 + 255) / 256), 256, 0, stream>>>(hs, hsb, ROWS * DMODEL / 4);
  transpose_cast<<<dim3((NH * DQK) / 32, DMODEL / 32), 256, 0, stream>>>(Wq, wqt, DMODEL, NH * DQK);
  transpose_cast<<<dim3((NH * DQK) / 32, DMODEL / 32), 256, 0, stream>>>(Wk, wkt, DMODEL, NH * DQK);
  transpose_cast<<<dim3((NH * DV) / 32, DMODEL / 32), 256, 0, stream>>>(Wv, wvt, DMODEL, NH * DV);
  transpose_cast<<<dim3(DMODEL / 32, DMODEL / 32), 256, 0, stream>>>(Wo, wot, DMODEL, DMODEL);

  // projections (MFMA): merged q|k (N=512), v (N=1024)
  gemm_mfma<<<dim3(512 / 128, ROWS / 128), 256, 0, stream>>>(hsb, wqt, qkb, ROWS, 512, DMODEL);
  gemm_mfma<<<dim3((NH * DV) / 128, ROWS / 128), 256, 0, stream>>>(hsb, wvt, vb, ROWS, NH * DV, DMODEL);

  // chunked causal linear attention
  chunk_sums<<<dim3(NCH, BATCH * NH), 320, 0, stream>>>(qkb, vb, Sb, ub);
  prefix_scan<<<dim3(BATCH * NH * FDIM), 64, 0, stream>>>(Sb, ub);
  attn_mfma<<<dim3(NCH, BATCH * NH), 256, 0, stream>>>(qkb, vb, Sb, ub, yb);

  // output projection (MFMA)
  gemm_mfma<<<dim3(DMODEL / 128, ROWS / 128), 256, 0, stream>>>(yb, wot, out, ROWS, DMODEL, DMODEL);
}